// Round 7
// baseline (614.019 us; speedup 1.0000x reference)
//
#include <hip/hip_runtime.h>
#include <hip/hip_bf16.h>
#include <cstdint>

// Fused: ConvTranspose2d(128->256, k=4, s=2, p=1) + MaxPool2 + Hardtanh + mean + tanh
// B=64, Cin=128, Cout=256, H=W=64. Output [64,256,1,1] fp32.
//
// R7: regime accepted = 1 wave/SIMD @ 256-reg cap (gfx950 per-SIMD pool == 256
// wave-slots; 2 waves/SIMD would need <=128 regs but accumulators alone are 128
// -- proven dead end R2/R3/R4/R6). Spill eliminated by SHRINKING DEMAND, not
// fighting launch_bounds: runtime (unroll-1) q/t tap loops + immediate-LUT tap
// decode stop the scheduler from hoisting 16 taps' loads/addressing (R5's ~350-reg
// demand -> ~200). Structure = R5: 256 thr, 64 KB swizzled x-tile, weights
// straight from L2, barrier-free main loop, 64 MFMA per tap hides load latency.

typedef __attribute__((ext_vector_type(8))) short short8;
typedef __attribute__((ext_vector_type(4))) float f32x4;

__device__ __forceinline__ void async16(const void* g, void* l) {
  __builtin_amdgcn_global_load_lds(
      reinterpret_cast<const unsigned int __attribute__((address_space(1)))*>(
          reinterpret_cast<uintptr_t>(g)),
      reinterpret_cast<unsigned int __attribute__((address_space(3)))*>(
          reinterpret_cast<uintptr_t>(l)),
      16, 0, 0);
}

__device__ __forceinline__ unsigned short f2bf(float f) {
  union { float f; unsigned int u; } v; v.f = f;
  unsigned int u = v.u;
  return (unsigned short)((u + 0x7fffu + ((u >> 16) & 1u)) >> 16);
}

__device__ __forceinline__ short8 and_mask(short8 v, unsigned m) {
  union { short8 s; unsigned u[4]; } x;
  x.s = v;
  x.u[0] &= m; x.u[1] &= m; x.u[2] &= m; x.u[3] &= m;
  return x.s;
}

// ---------------- Pass A: x NCHW f32 -> NHWC bf16 ----------------
__global__ __launch_bounds__(256) void k_xpose(const float* __restrict__ x,
                                               unsigned short* __restrict__ xT) {
  __shared__ float tile[64][132];
  int bid = blockIdx.x;
  int b = bid >> 6, h = bid & 63;
  const float* src = x + (size_t)b * 524288 + h * 64;
  int w = threadIdx.x & 63, cg = threadIdx.x >> 6;
#pragma unroll
  for (int cc = 0; cc < 32; ++cc) {
    int cin = cc * 4 + cg;
    tile[w][cin] = src[(size_t)cin * 4096 + w];
  }
  __syncthreads();
  unsigned short* dst = xT + (size_t)(b * 64 + h) * 8192;
#pragma unroll
  for (int it = 0; it < 4; ++it) {
    int e = it * 2048 + threadIdx.x * 8;
    int ww = e >> 7, cin = e & 127;
    unsigned int pk[4];
#pragma unroll
    for (int j = 0; j < 4; ++j) {
      unsigned int lo = f2bf(tile[ww][cin + 2 * j]);
      unsigned int hi = f2bf(tile[ww][cin + 2 * j + 1]);
      pk[j] = lo | (hi << 16);
    }
    *reinterpret_cast<uint4*>(dst + e) = make_uint4(pk[0], pk[1], pk[2], pk[3]);
  }
}

// ---------------- Pass B: w [cin][cout][kh][kw] f32 -> wT [kh*4+kw][cout][cin] bf16 ----
__global__ __launch_bounds__(256) void k_wpack(const float* __restrict__ w,
                                               unsigned short* __restrict__ wT) {
  int o = blockIdx.x * 256 + threadIdx.x;
  int cin = o & 127;
  int cout = (o >> 7) & 255;
  int khkw = o >> 15;
  int kh = khkw >> 2, kw = khkw & 3;
  float f = w[((size_t)cin * 256 + cout) * 16 + kh * 4 + kw];
  wT[o] = f2bf(f);
}

// ---------------- Main fused kernel ----------------
// LDS: x tile [4 rows][64 cols][128 cin] bf16 = 65536 B. No weight LDS.
#define LDS_TOTAL 65536

__global__ __launch_bounds__(256) void k_main(
    const unsigned short* __restrict__ xT,
    const unsigned short* __restrict__ wT,
    const float* __restrict__ bias,
    float* __restrict__ acc) {
  extern __shared__ char smem[];
  const int bid = blockIdx.x;
  const int pr  = bid & 31;         // pooled rows 2pr, 2pr+1
  const int nt  = (bid >> 5) & 1;   // cout half (consecutive bids share nt,b -> L2 reuse)
  const int b   = bid >> 6;
  const int n0  = nt * 128;
  const int tid  = threadIdx.x;
  const int lane = tid & 63;
  const int wid  = tid >> 6;   // 0..3
  const int wm   = wid >> 1;   // pooled row 2pr+wm
  const int wn   = wid & 1;    // cout 64-half
  const int l15  = lane & 15;
  const int l4   = lane >> 4;

  // ---- stage x tile [4][64][128]: tile row r <- input row 2pr-1+r ----
  {
    const char* xTb = (const char*)xT + (size_t)b * 1048576;  // 64 rows * 16384 B
#pragma unroll
    for (int it = 0; it < 16; ++it) {
      const int gbase = it * 4096 + wid * 1024;   // wave-uniform chunk (within one row)
      const int g = gbase + lane * 16;
      const int r = g >> 14;                      // 0..3, wave-uniform per chunk
      const int ir = 2 * pr - 1 + r;
      if ((unsigned)ir < 64u) {
        const int rc = g >> 8;                    // row*64+col index
        const int key = (rc & 7) << 4;
        const char* src = xTb + ir * 16384 + (rc & 63) * 256 + ((g & 255) ^ key);
        async16(src, smem + gbase);               // HW adds lane*16 (linear dest)
      } else {
        *reinterpret_cast<f32x4*>(smem + g) = (f32x4){0.f, 0.f, 0.f, 0.f};
      }
    }
  }
  __syncthreads();   // the ONLY barrier: x tile read-only from here on

  const unsigned kmneg = (l15 == 0)  ? 0u : ~0u;  // kill col -1 lane
  const unsigned kmpos = (l15 == 15) ? 0u : ~0u;  // kill col 64 lane

  f32x4 rm[4][4];
#pragma unroll
  for (int mi = 0; mi < 4; ++mi)
#pragma unroll
    for (int ni = 0; ni < 4; ++ni)
      rm[mi][ni] = (f32x4){-1e30f, -1e30f, -1e30f, -1e30f};

  // B global addressing: wT[khkw][cout][cin] bf16; this lane reads
  // cout = n0 + wn*64 + ni*16 + l15, cin = kk*32 + l4*8  (16B per load)
  const char* wb0 = (const char*)wT + (size_t)n0 * 256;
  const int boff = (wn * 64 + l15) * 256 + l4 * 16;   // + ni*4096 + kk*64

#pragma unroll 1
  for (int q = 0; q < 4; ++q) {            // runtime loop: caps register demand
    const int qh = q >> 1, qw = q & 1;
    f32x4 accf[4][4];
#pragma unroll
    for (int mi = 0; mi < 4; ++mi)
#pragma unroll
      for (int ni = 0; ni < 4; ++ni) accf[mi][ni] = (f32x4){0.f, 0.f, 0.f, 0.f};

#pragma unroll 1
    for (int t = 0; t < 4; ++t) {          // runtime loop
      const int th = t >> 1, tw = t & 1;
      // tap LUTs as packed immediates: KHt{{1,3},{2,0}} -> nibbles 0x0231
      const int kh = (0x0231 >> (4 * (2 * qh + th))) & 15;
      const int kw = (0x0231 >> (4 * (2 * qw + tw))) & 15;
      const int dr = th * (2 * qh - 1);    // DHt{{0,-1},{0,1}}
      const int dw = tw * (2 * qw - 1);
      const unsigned m0 = (dw < 0) ? kmneg : ~0u;
      const unsigned m3 = (dw > 0) ? kmpos : ~0u;
      const char* wb = wb0 + (kh * 4 + kw) * 65536;
      const int ar = wm + 1 + dr;          // x tile row (0..3)
      int aoff[4], akey[4];
#pragma unroll
      for (int mi = 0; mi < 4; ++mi) {
        int col = mi * 16 + l15 + dw;
        int colc = col < 0 ? 0 : (col > 63 ? 63 : col);
        int rc = ar * 64 + colc;
        aoff[mi] = rc * 256 + l4 * 16;
        akey[mi] = (rc & 7) << 4;
      }
#pragma unroll
      for (int kk = 0; kk < 4; ++kk) {
        short8 a[4], bb[4];
#pragma unroll
        for (int ni = 0; ni < 4; ++ni)
          bb[ni] = *reinterpret_cast<const short8*>(wb + boff + ni * 4096 + kk * 64);
#pragma unroll
        for (int mi = 0; mi < 4; ++mi)
          a[mi] = *reinterpret_cast<const short8*>(smem + ((aoff[mi] + kk * 64) ^ akey[mi]));
        a[0] = and_mask(a[0], m0);
        a[3] = and_mask(a[3], m3);
#pragma unroll
        for (int mi = 0; mi < 4; ++mi)
#pragma unroll
          for (int ni = 0; ni < 4; ++ni)
            accf[mi][ni] = __builtin_amdgcn_mfma_f32_16x16x32_bf16(a[mi], bb[ni], accf[mi][ni], 0, 0, 0);
      }
    }
    // parity q finished: fold into running max
#pragma unroll
    for (int mi = 0; mi < 4; ++mi)
#pragma unroll
      for (int ni = 0; ni < 4; ++ni)
#pragma unroll
        for (int rr = 0; rr < 4; ++rr)
          rm[mi][ni][rr] = fmaxf(rm[mi][ni][rr], accf[mi][ni][rr]);
  }

  // ---- epilogue: +bias, clamp, sum pixels, wave-reduce, atomicAdd ----
#pragma unroll
  for (int ni = 0; ni < 4; ++ni) {
    const int cout = n0 + wn * 64 + ni * 16 + l15;
    const float bv = bias[cout];
    float s = 0.f;
#pragma unroll
    for (int mi = 0; mi < 4; ++mi)
#pragma unroll
      for (int rr = 0; rr < 4; ++rr) {
        float v = rm[mi][ni][rr] + bv;
        v = fminf(1.f, fmaxf(-1.f, v));
        s += v;
      }
    s += __shfl_xor(s, 16, 64);
    s += __shfl_xor(s, 32, 64);
    if (lane < 16) atomicAdd(&acc[b * 256 + cout], s);
  }
}

// ---------------- finalize ----------------
__global__ __launch_bounds__(256) void k_fin(const float* __restrict__ acc,
                                             float* __restrict__ out) {
  int i = blockIdx.x * 256 + threadIdx.x;
  out[i] = tanhf(acc[i] * (1.0f / 4096.0f));
}

extern "C" void kernel_launch(void* const* d_in, const int* in_sizes, int n_in,
                              void* d_out, int out_size, void* d_ws, size_t ws_size,
                              hipStream_t stream) {
  const float* x    = (const float*)d_in[0];
  const float* w    = (const float*)d_in[1];
  const float* bias = (const float*)d_in[2];
  float* out = (float*)d_out;
  char* ws = (char*)d_ws;

  float* acc          = (float*)ws;                                // 65536 B
  unsigned short* xT  = (unsigned short*)(ws + 65536);             // 67108864 B
  unsigned short* wT  = (unsigned short*)(ws + 65536 + 67108864);  // 1048576 B

  hipMemsetAsync(acc, 0, 65536, stream);
  k_xpose<<<4096, 256, 0, stream>>>(x, xT);
  k_wpack<<<2048, 256, 0, stream>>>(w, wT);

  hipFuncSetAttribute(reinterpret_cast<const void*>(k_main),
                      hipFuncAttributeMaxDynamicSharedMemorySize, LDS_TOTAL);
  k_main<<<4096, 256, LDS_TOTAL, stream>>>(xT, wT, bias, acc);
  k_fin<<<64, 256, 0, stream>>>(acc, out);
}

// Round 8
// 554.904 us; speedup vs baseline: 1.1065x; 1.1065x over previous
//
#include <hip/hip_runtime.h>
#include <hip/hip_bf16.h>
#include <cstdint>

// Fused: ConvTranspose2d(128->256, k=4, s=2, p=1) + MaxPool2 + Hardtanh + mean + tanh
// B=64, Cin=128, Cout=256, H=W=64. Output [64,256,1,1] fp32.
//
// R8 = R7 + register double-buffered B prefetch (the single change).
// R7 post-mortem: spill fixed (WRITE 4 MB, VGPR 148) but MfmaUtil 18.6% --
// B loads from L2 were load-then-use, fully exposing ~200-500 cyc latency at
// 1 wave/SIMD. Now bb[2][4] phase buffers (unroll-static indices): loads for
// kk+1 (or next tap's kk=0) issue BEFORE kk's 16 MFMAs (310-cyc shadow > L2
// latency), so the vmcnt wait lands after the MFMA block. Demand ~210 < 256.

typedef __attribute__((ext_vector_type(8))) short short8;
typedef __attribute__((ext_vector_type(4))) float f32x4;

__device__ __forceinline__ void async16(const void* g, void* l) {
  __builtin_amdgcn_global_load_lds(
      reinterpret_cast<const unsigned int __attribute__((address_space(1)))*>(
          reinterpret_cast<uintptr_t>(g)),
      reinterpret_cast<unsigned int __attribute__((address_space(3)))*>(
          reinterpret_cast<uintptr_t>(l)),
      16, 0, 0);
}

__device__ __forceinline__ unsigned short f2bf(float f) {
  union { float f; unsigned int u; } v; v.f = f;
  unsigned int u = v.u;
  return (unsigned short)((u + 0x7fffu + ((u >> 16) & 1u)) >> 16);
}

__device__ __forceinline__ short8 and_mask(short8 v, unsigned m) {
  union { short8 s; unsigned u[4]; } x;
  x.s = v;
  x.u[0] &= m; x.u[1] &= m; x.u[2] &= m; x.u[3] &= m;
  return x.s;
}

// ---------------- Pass A: x NCHW f32 -> NHWC bf16 ----------------
__global__ __launch_bounds__(256) void k_xpose(const float* __restrict__ x,
                                               unsigned short* __restrict__ xT) {
  __shared__ float tile[64][132];
  int bid = blockIdx.x;
  int b = bid >> 6, h = bid & 63;
  const float* src = x + (size_t)b * 524288 + h * 64;
  int w = threadIdx.x & 63, cg = threadIdx.x >> 6;
#pragma unroll
  for (int cc = 0; cc < 32; ++cc) {
    int cin = cc * 4 + cg;
    tile[w][cin] = src[(size_t)cin * 4096 + w];
  }
  __syncthreads();
  unsigned short* dst = xT + (size_t)(b * 64 + h) * 8192;
#pragma unroll
  for (int it = 0; it < 4; ++it) {
    int e = it * 2048 + threadIdx.x * 8;
    int ww = e >> 7, cin = e & 127;
    unsigned int pk[4];
#pragma unroll
    for (int j = 0; j < 4; ++j) {
      unsigned int lo = f2bf(tile[ww][cin + 2 * j]);
      unsigned int hi = f2bf(tile[ww][cin + 2 * j + 1]);
      pk[j] = lo | (hi << 16);
    }
    *reinterpret_cast<uint4*>(dst + e) = make_uint4(pk[0], pk[1], pk[2], pk[3]);
  }
}

// ---------------- Pass B: w [cin][cout][kh][kw] f32 -> wT [kh*4+kw][cout][cin] bf16 ----
__global__ __launch_bounds__(256) void k_wpack(const float* __restrict__ w,
                                               unsigned short* __restrict__ wT) {
  int o = blockIdx.x * 256 + threadIdx.x;
  int cin = o & 127;
  int cout = (o >> 7) & 255;
  int khkw = o >> 15;
  int kh = khkw >> 2, kw = khkw & 3;
  float f = w[((size_t)cin * 256 + cout) * 16 + kh * 4 + kw];
  wT[o] = f2bf(f);
}

// ---------------- Main fused kernel ----------------
// LDS: x tile [4 rows][64 cols][128 cin] bf16 = 65536 B. No weight LDS.
#define LDS_TOTAL 65536

__global__ __launch_bounds__(256) void k_main(
    const unsigned short* __restrict__ xT,
    const unsigned short* __restrict__ wT,
    const float* __restrict__ bias,
    float* __restrict__ acc) {
  extern __shared__ char smem[];
  const int bid = blockIdx.x;
  const int pr  = bid & 31;         // pooled rows 2pr, 2pr+1
  const int nt  = (bid >> 5) & 1;   // cout half (consecutive bids share nt,b -> L2 reuse)
  const int b   = bid >> 6;
  const int n0  = nt * 128;
  const int tid  = threadIdx.x;
  const int lane = tid & 63;
  const int wid  = tid >> 6;   // 0..3
  const int wm   = wid >> 1;   // pooled row 2pr+wm
  const int wn   = wid & 1;    // cout 64-half
  const int l15  = lane & 15;
  const int l4   = lane >> 4;

  // ---- stage x tile [4][64][128]: tile row r <- input row 2pr-1+r ----
  {
    const char* xTb = (const char*)xT + (size_t)b * 1048576;  // 64 rows * 16384 B
#pragma unroll
    for (int it = 0; it < 16; ++it) {
      const int gbase = it * 4096 + wid * 1024;   // wave-uniform chunk (within one row)
      const int g = gbase + lane * 16;
      const int r = g >> 14;                      // 0..3, wave-uniform per chunk
      const int ir = 2 * pr - 1 + r;
      if ((unsigned)ir < 64u) {
        const int rc = g >> 8;                    // row*64+col index
        const int key = (rc & 7) << 4;
        const char* src = xTb + ir * 16384 + (rc & 63) * 256 + ((g & 255) ^ key);
        async16(src, smem + gbase);               // HW adds lane*16 (linear dest)
      } else {
        *reinterpret_cast<f32x4*>(smem + g) = (f32x4){0.f, 0.f, 0.f, 0.f};
      }
    }
  }
  __syncthreads();   // the ONLY barrier: x tile read-only from here on

  const unsigned kmneg = (l15 == 0)  ? 0u : ~0u;  // kill col -1 lane
  const unsigned kmpos = (l15 == 15) ? 0u : ~0u;  // kill col 64 lane

  f32x4 rm[4][4];
#pragma unroll
  for (int mi = 0; mi < 4; ++mi)
#pragma unroll
    for (int ni = 0; ni < 4; ++ni)
      rm[mi][ni] = (f32x4){-1e30f, -1e30f, -1e30f, -1e30f};

  // B global addressing: wT[khkw][cout][cin] bf16; this lane reads
  // cout = n0 + wn*64 + ni*16 + l15, cin = kk*32 + l4*8  (16B per load)
  const char* wb0 = (const char*)wT + (size_t)n0 * 256;
  const int boff = (wn * 64 + l15) * 256 + l4 * 16;   // + ni*4096 + kk*64

  // ---- B pipeline: bb[2][4] phase buffers; prologue = tap0 (khkw=5), kk=0 ----
  short8 bb[2][4];
  {
    const char* wb = wb0 + 5 * 65536;
#pragma unroll
    for (int ni = 0; ni < 4; ++ni)
      bb[0][ni] = *reinterpret_cast<const short8*>(wb + boff + ni * 4096);
  }

#pragma unroll 1
  for (int q = 0; q < 4; ++q) {            // runtime loop: caps register demand
    const int qh = q >> 1, qw = q & 1;
    f32x4 accf[4][4];
#pragma unroll
    for (int mi = 0; mi < 4; ++mi)
#pragma unroll
      for (int ni = 0; ni < 4; ++ni) accf[mi][ni] = (f32x4){0.f, 0.f, 0.f, 0.f};

#pragma unroll 1
    for (int t = 0; t < 4; ++t) {          // runtime loop
      const int th = t >> 1, tw = t & 1;
      // tap LUTs as packed immediates: KHt{{1,3},{2,0}} -> nibbles 0x0231
      const int kh = (0x0231 >> (4 * (2 * qh + th))) & 15;
      const int kw = (0x0231 >> (4 * (2 * qw + tw))) & 15;
      const int dr = th * (2 * qh - 1);    // DHt{{0,-1},{0,1}}
      const int dw = tw * (2 * qw - 1);
      const unsigned m0 = (dw < 0) ? kmneg : ~0u;
      const unsigned m3 = (dw > 0) ? kmpos : ~0u;
      const char* wb = wb0 + (kh * 4 + kw) * 65536;

      // next tap's weight base (for cross-tap kk=0 prefetch)
      const int idx  = q * 4 + t;
      const int nidx = (idx + 1) & 15;
      const int q2 = nidx >> 2, t2 = nidx & 3;
      const int kh2 = (0x0231 >> (4 * (2 * (q2 >> 1) + (t2 >> 1)))) & 15;
      const int kw2 = (0x0231 >> (4 * (2 * (q2 & 1) + (t2 & 1)))) & 15;
      const char* wbn = wb0 + (kh2 * 4 + kw2) * 65536;

      const int ar = wm + 1 + dr;          // x tile row (0..3)
      int aoff[4], akey[4];
#pragma unroll
      for (int mi = 0; mi < 4; ++mi) {
        int col = mi * 16 + l15 + dw;
        int colc = col < 0 ? 0 : (col > 63 ? 63 : col);
        int rc = ar * 64 + colc;
        aoff[mi] = rc * 256 + l4 * 16;
        akey[mi] = (rc & 7) << 4;
      }
#pragma unroll
      for (int kk = 0; kk < 4; ++kk) {
        // issue next-phase B loads FIRST: kk+1 of this tap, or kk=0 of next tap
        const char* pb = (kk < 3) ? (wb + (kk + 1) * 64) : wbn;
#pragma unroll
        for (int ni = 0; ni < 4; ++ni)
          bb[(kk + 1) & 1][ni] =
              *reinterpret_cast<const short8*>(pb + boff + ni * 4096);
        // A fragments from LDS (latency hidden by prior kk's MFMA drain)
        short8 a[4];
#pragma unroll
        for (int mi = 0; mi < 4; ++mi)
          a[mi] = *reinterpret_cast<const short8*>(smem + ((aoff[mi] + kk * 64) ^ akey[mi]));
        if (dw < 0) a[0] = and_mask(a[0], m0);
        if (dw > 0) a[3] = and_mask(a[3], m3);
        // 16 MFMAs consume the CURRENT phase (loaded during previous step)
#pragma unroll
        for (int mi = 0; mi < 4; ++mi)
#pragma unroll
          for (int ni = 0; ni < 4; ++ni)
            accf[mi][ni] = __builtin_amdgcn_mfma_f32_16x16x32_bf16(
                a[mi], bb[kk & 1][ni], accf[mi][ni], 0, 0, 0);
      }
    }
    // parity q finished: fold into running max
#pragma unroll
    for (int mi = 0; mi < 4; ++mi)
#pragma unroll
      for (int ni = 0; ni < 4; ++ni)
#pragma unroll
        for (int rr = 0; rr < 4; ++rr)
          rm[mi][ni][rr] = fmaxf(rm[mi][ni][rr], accf[mi][ni][rr]);
  }

  // ---- epilogue: +bias, clamp, sum pixels, wave-reduce, atomicAdd ----
#pragma unroll
  for (int ni = 0; ni < 4; ++ni) {
    const int cout = n0 + wn * 64 + ni * 16 + l15;
    const float bv = bias[cout];
    float s = 0.f;
#pragma unroll
    for (int mi = 0; mi < 4; ++mi)
#pragma unroll
      for (int rr = 0; rr < 4; ++rr) {
        float v = rm[mi][ni][rr] + bv;
        v = fminf(1.f, fmaxf(-1.f, v));
        s += v;
      }
    s += __shfl_xor(s, 16, 64);
    s += __shfl_xor(s, 32, 64);
    if (lane < 16) atomicAdd(&acc[b * 256 + cout], s);
  }
}

// ---------------- finalize ----------------
__global__ __launch_bounds__(256) void k_fin(const float* __restrict__ acc,
                                             float* __restrict__ out) {
  int i = blockIdx.x * 256 + threadIdx.x;
  out[i] = tanhf(acc[i] * (1.0f / 4096.0f));
}

extern "C" void kernel_launch(void* const* d_in, const int* in_sizes, int n_in,
                              void* d_out, int out_size, void* d_ws, size_t ws_size,
                              hipStream_t stream) {
  const float* x    = (const float*)d_in[0];
  const float* w    = (const float*)d_in[1];
  const float* bias = (const float*)d_in[2];
  float* out = (float*)d_out;
  char* ws = (char*)d_ws;

  float* acc          = (float*)ws;                                // 65536 B
  unsigned short* xT  = (unsigned short*)(ws + 65536);             // 67108864 B
  unsigned short* wT  = (unsigned short*)(ws + 65536 + 67108864);  // 1048576 B

  hipMemsetAsync(acc, 0, 65536, stream);
  k_xpose<<<4096, 256, 0, stream>>>(x, xT);
  k_wpack<<<2048, 256, 0, stream>>>(w, wT);

  hipFuncSetAttribute(reinterpret_cast<const void*>(k_main),
                      hipFuncAttributeMaxDynamicSharedMemorySize, LDS_TOTAL);
  k_main<<<4096, 256, LDS_TOTAL, stream>>>(xT, wT, bias, acc);
  k_fin<<<64, 256, 0, stream>>>(acc, out);
}

// Round 9
// 403.568 us; speedup vs baseline: 1.5215x; 1.3750x over previous
//
#include <hip/hip_runtime.h>
#include <hip/hip_bf16.h>
#include <cstdint>

// Fused: ConvTranspose2d(128->256, k=4, s=2, p=1) + MaxPool2 + Hardtanh + mean + tanh
// B=64, Cin=128, Cout=256, H=W=64. Output [64,256,1,1] fp32.
//
// R9: 2 waves/SIMD achieved by SHRINKING THE WAVE TILE (not fighting the 128-reg
// cap): 512 thr / 8 waves, wave tile 64px x 32cout -> acc 64 regs, demand ~116 < 128.
// Weights back in LDS (R8 lesson: B-from-L2 needs 52 B/cyc vs 56 B/cyc per-CU L2
// port -- architecturally capped). LDS = 64KB x-tile + 2x32KB w-dbuf = 128KB ->
// 1 block/CU -> 2 waves/SIMD; __launch_bounds__(512,1) empirically caps at 128 (R6),
// which is exactly the budget. R1 structure (stage-next / compute / barrier per tap).

typedef __attribute__((ext_vector_type(8))) short short8;
typedef __attribute__((ext_vector_type(4))) float f32x4;

__device__ __forceinline__ void async16(const void* g, void* l) {
  __builtin_amdgcn_global_load_lds(
      reinterpret_cast<const unsigned int __attribute__((address_space(1)))*>(
          reinterpret_cast<uintptr_t>(g)),
      reinterpret_cast<unsigned int __attribute__((address_space(3)))*>(
          reinterpret_cast<uintptr_t>(l)),
      16, 0, 0);
}

__device__ __forceinline__ unsigned short f2bf(float f) {
  union { float f; unsigned int u; } v; v.f = f;
  unsigned int u = v.u;
  return (unsigned short)((u + 0x7fffu + ((u >> 16) & 1u)) >> 16);
}

__device__ __forceinline__ short8 and_mask(short8 v, unsigned m) {
  union { short8 s; unsigned u[4]; } x;
  x.s = v;
  x.u[0] &= m; x.u[1] &= m; x.u[2] &= m; x.u[3] &= m;
  return x.s;
}

// ---------------- Pass A: x NCHW f32 -> NHWC bf16 ----------------
__global__ __launch_bounds__(256) void k_xpose(const float* __restrict__ x,
                                               unsigned short* __restrict__ xT) {
  __shared__ float tile[64][132];
  int bid = blockIdx.x;
  int b = bid >> 6, h = bid & 63;
  const float* src = x + (size_t)b * 524288 + h * 64;
  int w = threadIdx.x & 63, cg = threadIdx.x >> 6;
#pragma unroll
  for (int cc = 0; cc < 32; ++cc) {
    int cin = cc * 4 + cg;
    tile[w][cin] = src[(size_t)cin * 4096 + w];
  }
  __syncthreads();
  unsigned short* dst = xT + (size_t)(b * 64 + h) * 8192;
#pragma unroll
  for (int it = 0; it < 4; ++it) {
    int e = it * 2048 + threadIdx.x * 8;
    int ww = e >> 7, cin = e & 127;
    unsigned int pk[4];
#pragma unroll
    for (int j = 0; j < 4; ++j) {
      unsigned int lo = f2bf(tile[ww][cin + 2 * j]);
      unsigned int hi = f2bf(tile[ww][cin + 2 * j + 1]);
      pk[j] = lo | (hi << 16);
    }
    *reinterpret_cast<uint4*>(dst + e) = make_uint4(pk[0], pk[1], pk[2], pk[3]);
  }
}

// ---------------- Pass B: w [cin][cout][kh][kw] f32 -> wT [kh*4+kw][cout][cin] bf16 ----
__global__ __launch_bounds__(256) void k_wpack(const float* __restrict__ w,
                                               unsigned short* __restrict__ wT) {
  int o = blockIdx.x * 256 + threadIdx.x;
  int cin = o & 127;
  int cout = (o >> 7) & 255;
  int khkw = o >> 15;
  int kh = khkw >> 2, kw = khkw & 3;
  float f = w[((size_t)cin * 256 + cout) * 16 + kh * 4 + kw];
  wT[o] = f2bf(f);
}

// ---------------- Main fused kernel ----------------
// LDS: x tile [4][64][128] bf16 = 65536 B; weight dbuf 2 x [128][128] bf16 = 65536 B.
#define WBUF0_B  65536
#define WBUF_SZ  32768
#define LDS_TOTAL 131072

__global__ __launch_bounds__(512, 1) void k_main(
    const unsigned short* __restrict__ xT,
    const unsigned short* __restrict__ wT,
    const float* __restrict__ bias,
    float* __restrict__ acc) {
  extern __shared__ char smem[];
  const int bid = blockIdx.x;
  const int pr  = bid & 31;         // pooled rows 2pr, 2pr+1
  const int nt  = (bid >> 5) & 1;   // cout half
  const int b   = bid >> 6;
  const int n0  = nt * 128;
  const int tid  = threadIdx.x;
  const int lane = tid & 63;
  const int wid  = tid >> 6;   // 0..7
  const int wm   = wid >> 2;   // pooled row 2pr+wm (0..1)
  const int wn   = wid & 3;    // cout quarter n0+wn*32 (0..3)
  const int l15  = lane & 15;
  const int l4   = lane >> 4;

  // ---- stage x tile [4][64][128]: tile row r <- input row 2pr-1+r ----
  {
    const char* xTb = (const char*)xT + (size_t)b * 1048576;  // 64 rows * 16384 B
#pragma unroll
    for (int it = 0; it < 8; ++it) {
      const int gbase = it * 8192 + wid * 1024;   // wave-uniform chunk
      const int g = gbase + lane * 16;
      const int r = g >> 14;                      // wave-uniform within chunk
      const int ir = 2 * pr - 1 + r;
      if ((unsigned)ir < 64u) {
        const int rc = g >> 8;
        const int key = (rc & 7) << 4;
        const char* src = xTb + ir * 16384 + (rc & 63) * 256 + ((g & 255) ^ key);
        async16(src, smem + gbase);               // HW adds lane*16 (linear dest)
      } else {
        *reinterpret_cast<f32x4*>(smem + g) = (f32x4){0.f, 0.f, 0.f, 0.f};
      }
    }
  }

  auto stage_w = [&](int khkw, int buf) {
    char* dstbase = smem + WBUF0_B + buf * WBUF_SZ;
    const char* g0 = (const char*)wT + ((size_t)khkw * 256 + n0) * 256;
#pragma unroll
    for (int it = 0; it < 4; ++it) {
      const int gbase = wid * 4096 + it * 1024;
      const int g = gbase + lane * 16;
      const int cl = g >> 8;
      const int key = (cl & 7) << 4;
      async16(g0 + (g & ~255) + ((g & 255) ^ key), dstbase + gbase);
    }
  };

  stage_w(5, 0);     // tap 0: kh=1,kw=1 -> khkw=5
  __syncthreads();   // drains x-stage + w-stage(0)

  const unsigned kmneg = (l15 == 0)  ? 0u : ~0u;  // kill col -1 lane
  const unsigned kmpos = (l15 == 15) ? 0u : ~0u;  // kill col 64 lane

  f32x4 rm[4][2];
#pragma unroll
  for (int mi = 0; mi < 4; ++mi)
#pragma unroll
    for (int ni = 0; ni < 2; ++ni)
      rm[mi][ni] = (f32x4){-1e30f, -1e30f, -1e30f, -1e30f};

  // B LDS addressing: wbuf[cout 0..127][cin 0..127]; lane reads
  // cl = wn*32 + ni*16 + l15, byte = cl*256 + l4*16 + kk*64, XOR (cl&7)<<4
  int boff[2], bkey[2];
#pragma unroll
  for (int ni = 0; ni < 2; ++ni) {
    int cl = wn * 32 + ni * 16 + l15;
    boff[ni] = cl * 256 + l4 * 16;
    bkey[ni] = (cl & 7) << 4;
  }

#pragma unroll 1
  for (int q = 0; q < 4; ++q) {            // runtime loop: caps register demand
    const int qh = q >> 1, qw = q & 1;
    f32x4 accf[4][2];
#pragma unroll
    for (int mi = 0; mi < 4; ++mi)
#pragma unroll
      for (int ni = 0; ni < 2; ++ni) accf[mi][ni] = (f32x4){0.f, 0.f, 0.f, 0.f};

#pragma unroll 1
    for (int t = 0; t < 4; ++t) {          // runtime loop
      const int th = t >> 1, tw = t & 1;
      const int dr = th * (2 * qh - 1);    // DHt{{0,-1},{0,1}}
      const int dw = tw * (2 * qw - 1);
      const unsigned m0 = (dw < 0) ? kmneg : ~0u;
      const unsigned m3 = (dw > 0) ? kmpos : ~0u;
      const int idx = q * 4 + t;

      if (idx < 15) {                      // prefetch next weight slice
        const int nidx = idx + 1;
        const int q2 = nidx >> 2, t2 = nidx & 3;
        const int kh2 = (0x0231 >> (4 * (2 * (q2 >> 1) + (t2 >> 1)))) & 15;
        const int kw2 = (0x0231 >> (4 * (2 * (q2 & 1) + (t2 & 1)))) & 15;
        stage_w(kh2 * 4 + kw2, nidx & 1);
      }

      const int ar = wm + 1 + dr;          // x tile row (0..3)
      int aoff[4], akey[4];
#pragma unroll
      for (int mi = 0; mi < 4; ++mi) {
        int col = mi * 16 + l15 + dw;
        int colc = col < 0 ? 0 : (col > 63 ? 63 : col);
        int rc = ar * 64 + colc;
        aoff[mi] = rc * 256 + l4 * 16;
        akey[mi] = (rc & 7) << 4;
      }
      const char* wbuf = smem + WBUF0_B + (idx & 1) * WBUF_SZ;
#pragma unroll
      for (int kk = 0; kk < 4; ++kk) {
        short8 a[4], bb[2];
#pragma unroll
        for (int ni = 0; ni < 2; ++ni)
          bb[ni] = *reinterpret_cast<const short8*>(wbuf + ((boff[ni] + kk * 64) ^ bkey[ni]));
#pragma unroll
        for (int mi = 0; mi < 4; ++mi)
          a[mi] = *reinterpret_cast<const short8*>(smem + ((aoff[mi] + kk * 64) ^ akey[mi]));
        a[0] = and_mask(a[0], m0);
        a[3] = and_mask(a[3], m3);
#pragma unroll
        for (int mi = 0; mi < 4; ++mi)
#pragma unroll
          for (int ni = 0; ni < 2; ++ni)
            accf[mi][ni] = __builtin_amdgcn_mfma_f32_16x16x32_bf16(
                a[mi], bb[ni], accf[mi][ni], 0, 0, 0);
      }
      __syncthreads();   // all waves done reading buf; next-tap staging complete
    }
    // parity q finished: fold into running max
#pragma unroll
    for (int mi = 0; mi < 4; ++mi)
#pragma unroll
      for (int ni = 0; ni < 2; ++ni)
#pragma unroll
        for (int rr = 0; rr < 4; ++rr)
          rm[mi][ni][rr] = fmaxf(rm[mi][ni][rr], accf[mi][ni][rr]);
  }

  // ---- epilogue: +bias, clamp, sum pixels, wave-reduce, atomicAdd ----
#pragma unroll
  for (int ni = 0; ni < 2; ++ni) {
    const int cout = n0 + wn * 32 + ni * 16 + l15;
    const float bv = bias[cout];
    float s = 0.f;
#pragma unroll
    for (int mi = 0; mi < 4; ++mi)
#pragma unroll
      for (int rr = 0; rr < 4; ++rr) {
        float v = rm[mi][ni][rr] + bv;
        v = fminf(1.f, fmaxf(-1.f, v));
        s += v;
      }
    s += __shfl_xor(s, 16, 64);
    s += __shfl_xor(s, 32, 64);
    if (lane < 16) atomicAdd(&acc[b * 256 + cout], s);
  }
}

// ---------------- finalize ----------------
__global__ __launch_bounds__(256) void k_fin(const float* __restrict__ acc,
                                             float* __restrict__ out) {
  int i = blockIdx.x * 256 + threadIdx.x;
  out[i] = tanhf(acc[i] * (1.0f / 4096.0f));
}

extern "C" void kernel_launch(void* const* d_in, const int* in_sizes, int n_in,
                              void* d_out, int out_size, void* d_ws, size_t ws_size,
                              hipStream_t stream) {
  const float* x    = (const float*)d_in[0];
  const float* w    = (const float*)d_in[1];
  const float* bias = (const float*)d_in[2];
  float* out = (float*)d_out;
  char* ws = (char*)d_ws;

  float* acc          = (float*)ws;                                // 65536 B
  unsigned short* xT  = (unsigned short*)(ws + 65536);             // 67108864 B
  unsigned short* wT  = (unsigned short*)(ws + 65536 + 67108864);  // 1048576 B

  hipMemsetAsync(acc, 0, 65536, stream);
  k_xpose<<<4096, 256, 0, stream>>>(x, xT);
  k_wpack<<<2048, 256, 0, stream>>>(w, wT);

  hipFuncSetAttribute(reinterpret_cast<const void*>(k_main),
                      hipFuncAttributeMaxDynamicSharedMemorySize, LDS_TOTAL);
  k_main<<<4096, 512, LDS_TOTAL, stream>>>(xT, wT, bias, acc);
  k_fin<<<64, 256, 0, stream>>>(acc, out);
}